// Round 1
// baseline (381.982 us; speedup 1.0000x reference)
//
#include <hip/hip_runtime.h>

#define N_NODES 10000
#define E_EDGES 150000
#define KNB     15
#define EBLOCKS 587   // ceil(E/256)
#define GEMMB   626   // 313 rowBlks(32 rows) x 2 colBlks(128 cols)

typedef unsigned short u16;
typedef __bf16 bf16x8 __attribute__((ext_vector_type(8)));
typedef float  f32x4  __attribute__((ext_vector_type(4)));

// ---------------------------------------------------------------------------
// Exact-ish bf16x3 split: a ~= hi + mid + lo. hi is RNE bf16 (Veltkamp step is
// exact in fp32), mid/lo truncated. Residual ~2^-25*|a|; dropped cross terms
// (mid*lo etc.) ~2^-26 => fp32-level accuracy with 6 MFMA terms (p+q<=2).
// ---------------------------------------------------------------------------
__device__ __forceinline__ void split3(float a, u16& h, u16& m, u16& l) {
    unsigned u = __float_as_uint(a);
    unsigned t = u + 0x7FFFu + ((u >> 16) & 1u);
    h = (u16)(t >> 16);
    float r1 = a - __uint_as_float(t & 0xFFFF0000u);
    unsigned u1 = __float_as_uint(r1);
    m = (u16)(u1 >> 16);
    float r2 = r1 - __uint_as_float(u1 & 0xFFFF0000u);
    l = (u16)(__float_as_uint(r2) >> 16);
}

// ---------------------------------------------------------------------------
// CSR count: parallel global atomics — NEVER single-block this (R7 lesson).
// ---------------------------------------------------------------------------
__global__ void count_kernel(const int* __restrict__ idxs, int* __restrict__ cnt, int e) {
    int i = blockIdx.x * blockDim.x + threadIdx.x;
    if (i < e) atomicAdd(&cnt[idxs[i]], 1);
}

// ---------------------------------------------------------------------------
// gemm_tile2 (MR=2) — weight-space folds only
// ---------------------------------------------------------------------------
__device__ __forceinline__
void gemm_tile2(const float* __restrict__ A, int K,
                const float* __restrict__ Blo, const float* __restrict__ Bhi, int ldB,
                float* __restrict__ C, int ldC, int M,
                int rowBlk, int colBlk) {
    __shared__ float As2[16][34];
    __shared__ float Bs2[16][64];
    int tid = threadIdx.x;
    int tn  = tid & 15, tm = tid >> 4;
    int arow = tid >> 3, acB = (tid & 7) << 1;
    int brow = tid >> 4, bcol = (tid & 15) << 2;
    int rowBase = rowBlk * 32, colBase = colBlk * 64;

    bool half = (Bhi != nullptr) && (colBase >= 128);
    const float* B = half ? Bhi : Blo;
    int bj = colBase - (half ? 128 : 0) + bcol;

    float2 av; float4 bv;
    auto loadA = [&](int k0, float2& dst) {
        int gr = rowBase + arow;
        if (gr < M) dst = *(const float2*)(A + (size_t)gr * K + k0 + acB);
        else { dst.x = dst.y = 0.f; }
    };
    auto loadB = [&](int k0, float4& dst) {
        dst = *(const float4*)(B + (size_t)(k0 + brow) * ldB + bj);
    };
    loadA(0, av); loadB(0, bv);

    float acc[2][4] = {};
    for (int k0 = 0; k0 < K; k0 += 16) {
        __syncthreads();
        As2[acB + 0][arow] = av.x; As2[acB + 1][arow] = av.y;
        *(float4*)&Bs2[brow][bcol] = bv;
        __syncthreads();
        if (k0 + 16 < K) { loadA(k0 + 16, av); loadB(k0 + 16, bv); }
#pragma unroll
        for (int k = 0; k < 16; ++k) {
            float4 b = *(const float4*)&Bs2[k][tn << 2];
            float2 a = *(const float2*)&As2[k][tm << 1];
            acc[0][0] = fmaf(a.x, b.x, acc[0][0]); acc[0][1] = fmaf(a.x, b.y, acc[0][1]);
            acc[0][2] = fmaf(a.x, b.z, acc[0][2]); acc[0][3] = fmaf(a.x, b.w, acc[0][3]);
            acc[1][0] = fmaf(a.y, b.x, acc[1][0]); acc[1][1] = fmaf(a.y, b.y, acc[1][1]);
            acc[1][2] = fmaf(a.y, b.z, acc[1][2]); acc[1][3] = fmaf(a.y, b.w, acc[1][3]);
        }
    }
#pragma unroll
    for (int i = 0; i < 2; ++i) {
        int row = rowBase + tm * 2 + i;
        if (row >= M) continue;
#pragma unroll
        for (int j = 0; j < 4; ++j)
            C[(size_t)row * ldC + colBase + (tn << 2) + j] = acc[i][j];
    }
}

// ---------------------------------------------------------------------------
// scanfold: block 0 = prefix-scan of cnt; blocks 1..40 = weight folds;
// blocks 41..56 = bf16x3 split + transpose of [mw1|nw1] (rows 0..783, zero-pad
// to 800) into Bt[3][256][800] (bf16 bits, Bt[p][col][k] = B[k][col]).
// ---------------------------------------------------------------------------
__global__ __launch_bounds__(256)
void scanfold_kernel(const float* __restrict__ mw2, const float* __restrict__ mb2,
                     const float* __restrict__ nw1, const float* __restrict__ nb2,
                     const float* __restrict__ nw2,
                     const float* __restrict__ m2w1, const float* __restrict__ m2b1,
                     const float* __restrict__ m2w2, const float* __restrict__ m2b2,
                     const float* __restrict__ n2w1, const float* __restrict__ n2b1,
                     float* __restrict__ M1, float* __restrict__ M2,
                     float* __restrict__ WH,
                     float* __restrict__ v1, float* __restrict__ v2,
                     float* __restrict__ bu2, float* __restrict__ bx2,
                     const int* __restrict__ cnt, int* __restrict__ eoff,
                     float* __restrict__ maskv, int* __restrict__ fillc,
                     const float* __restrict__ mw1, u16* __restrict__ Bt) {
    int b = blockIdx.x;
    if (b >= 41) {
        // ---- bsplit: 16 cols per block, LDS transpose then split3 ----
        __shared__ float Lt[800][17];
        int b2 = b - 41;
        int colBase = b2 * 16;
        const float* S = (colBase < 128) ? mw1 : nw1;
        int sc = colBase & 127;
        int tid = threadIdx.x;
        for (int i = 0; i < 50; ++i) {
            int row = (tid >> 4) + i * 16;
            Lt[row][tid & 15] = (row < 784) ? S[(size_t)row * 128 + sc + (tid & 15)] : 0.f;
        }
        __syncthreads();
        int col = tid >> 4, o = tid & 15;
        size_t dbase = (size_t)(colBase + col) * 800;
        for (int o2 = o; o2 < 100; o2 += 16) {
            u16 hs[8], ms[8], ls[8];
#pragma unroll
            for (int e = 0; e < 8; ++e) split3(Lt[o2 * 8 + e][col], hs[e], ms[e], ls[e]);
            auto pk = [](const u16* s) {
                uint4 v;
                v.x = s[0] | ((unsigned)s[1] << 16); v.y = s[2] | ((unsigned)s[3] << 16);
                v.z = s[4] | ((unsigned)s[5] << 16); v.w = s[6] | ((unsigned)s[7] << 16);
                return v;
            };
            *(uint4*)(Bt +          dbase + o2 * 8) = pk(hs);
            *(uint4*)(Bt + 204800 + dbase + o2 * 8) = pk(ms);
            *(uint4*)(Bt + 409600 + dbase + o2 * 8) = pk(ls);
        }
        return;
    }
    if (b == 0) {
        __shared__ int ssum[256];
        int tid = threadIdx.x;
        const int CH = 40;
        int base = tid * CH;
        int v[CH]; int s = 0;
#pragma unroll
        for (int q = 0; q < CH; ++q) {
            int i = base + q;
            v[q] = (i < N_NODES) ? cnt[i] : 0;
            s += v[q];
        }
        ssum[tid] = s;
        __syncthreads();
        for (int off = 1; off < 256; off <<= 1) {
            int t = (tid >= off) ? ssum[tid - off] : 0;
            __syncthreads();
            ssum[tid] += t;
            __syncthreads();
        }
        int ex = ssum[tid] - s;
#pragma unroll
        for (int q = 0; q < CH; ++q) {
            int i = base + q;
            if (i < N_NODES) {
                eoff[i]  = ex;
                maskv[i] = (v[q] > 0) ? 1.f : 0.f;
                fillc[i] = 0;
                ex += v[q];
            }
        }
        return;
    }
    b -= 1;
    if (b < 8) {
        gemm_tile2(mw2, 784, nw1 + 784 * 128, nullptr, 128, M1, 128, 128, b >> 1, b & 1);
    } else if (b < 16) {
        int t = b - 8;
        gemm_tile2(m2w2, 128, n2w1 + 128 * 128, nullptr, 128, M2, 128, 128, t >> 1, t & 1);
    } else if (b < 32) {
        int t = b - 16;
        gemm_tile2(nw2, 128, m2w1, n2w1, 128, WH, 256, 128, t >> 2, t & 3);
    } else {
        __shared__ float red[256];
        int t  = (b - 32) >> 1;
        int j  = ((b - 32) & 1) * 64 + (threadIdx.x & 63);
        int kq = threadIdx.x >> 6;
        const float* bvec; const float* Bv; const float* add; float* out; int Kv;
        if (t == 0)      { bvec = mb2;  Bv = nw1 + 784 * 128;  add = nullptr; out = v1;  Kv = 784; }
        else if (t == 1) { bvec = m2b2; Bv = n2w1 + 128 * 128; add = nullptr; out = v2;  Kv = 128; }
        else if (t == 2) { bvec = nb2;  Bv = m2w1;             add = m2b1;    out = bu2; Kv = 128; }
        else             { bvec = nb2;  Bv = n2w1;             add = n2b1;    out = bx2; Kv = 128; }
        float acc = 0.f;
        for (int k = kq; k < Kv; k += 4) acc = fmaf(bvec[k], Bv[k * 128 + j], acc);
        red[threadIdx.x] = acc;
        __syncthreads();
        if (threadIdx.x < 64) {
            float tot = red[threadIdx.x] + red[threadIdx.x + 64] +
                        red[threadIdx.x + 128] + red[threadIdx.x + 192];
            out[j] = tot + (add ? add[j] : 0.f);
        }
    }
}

// ---------------------------------------------------------------------------
// MFMA bf16x3 GEMM tile: 32 rows x 128 cols per block, K=784 padded to 800.
// 6 term-passes (hi*hi, hi*mid, mid*hi, hi*lo, mid*mid, lo*hi) fused into the
// k-loop: per 32-k tile stage all 3 A planes (on-the-fly split from fp32 x)
// and all 3 pre-split B planes, then 24 mfma_f32_16x16x32_bf16 per wave.
// LDS is fragment-linear ([plane][frag][lane][8]) -> all b128 reads are
// lane-contiguous = conflict-free; k-permutation inside a lane-group cancels
// between A and B fragments.
// ---------------------------------------------------------------------------
__device__ __forceinline__
void gemm_mfma(const float* __restrict__ A, const u16* __restrict__ Bt,
               const float* __restrict__ biasLo, const float* __restrict__ biasHi,
               const float* __restrict__ vhi, const float* __restrict__ rowmask,
               float* __restrict__ C, int gb) {
    __shared__ u16 Bs[3][8][64][8];   // 24 KB  [plane][colfrag][lane][e]
    __shared__ u16 As[3][2][64][8];   //  6 KB  [plane][rowfrag][lane][e]
    int tid  = threadIdx.x;
    int lane = tid & 63, w = tid >> 6;
    int rb = gb >> 1, cb = gb & 1;
    int rowBase = rb * 32, colBase = cb * 128;

    // A staging coords: thread -> (row, 4-wide k chunk)
    int ar  = tid >> 3;            // 0..31
    int akc = (tid & 7) << 2;      // 0,4,...,28
    int arow = rowBase + ar; if (arow > N_NODES - 1) arow = N_NODES - 1;
    const float* Ap = A + (size_t)arow * 784;
    int aL  = (ar & 15) + ((akc >> 3) << 4);   // frag lane
    int aE  = akc & 4;                         // element offset within octet
    int aRf = ar >> 4;

    // B staging: 6 chunks/thread, window wid = w*6+j -> (plane, colfrag)
    size_t bsrc[6]; int bp[6], bcf[6];
#pragma unroll
    for (int j = 0; j < 6; ++j) {
        int wid = w * 6 + j;
        int p = wid >> 3, cf = wid & 7;
        bp[j] = p; bcf[j] = cf;
        bsrc[j] = (size_t)p * 204800 +
                  (size_t)(colBase + cf * 16 + (lane & 15)) * 800 + ((lane >> 4) << 3);
    }

    float4 av; uint4 bv[6];
    auto loadT = [&](int k0) {
        int kk = akc + k0; if (kk >= 784) kk = 0;   // padded k: B plane is 0 there
        av = *(const float4*)(Ap + kk);
#pragma unroll
        for (int j = 0; j < 6; ++j) bv[j] = *(const uint4*)(Bt + bsrc[j] + k0);
    };
    ushort4 a3[3];
    auto splitA = [&]() {
        u16 h, m, l;
        split3(av.x, h, m, l); a3[0].x = h; a3[1].x = m; a3[2].x = l;
        split3(av.y, h, m, l); a3[0].y = h; a3[1].y = m; a3[2].y = l;
        split3(av.z, h, m, l); a3[0].z = h; a3[1].z = m; a3[2].z = l;
        split3(av.w, h, m, l); a3[0].w = h; a3[1].w = m; a3[2].w = l;
    };

    f32x4 acc[2][2];
    const f32x4 fz = {0.f, 0.f, 0.f, 0.f};
    acc[0][0] = fz; acc[0][1] = fz; acc[1][0] = fz; acc[1][1] = fz;

    loadT(0); splitA();
    for (int t = 0; t < 25; ++t) {
        __syncthreads();
#pragma unroll
        for (int p = 0; p < 3; ++p)
            *(ushort4*)&As[p][aRf][aL][aE] = a3[p];
#pragma unroll
        for (int j = 0; j < 6; ++j)
            *(uint4*)&Bs[bp[j]][bcf[j]][lane][0] = bv[j];
        __syncthreads();
        if (t < 24) loadT((t + 1) << 5);

        bf16x8 af[2][3], bfr[2][3];
#pragma unroll
        for (int rf = 0; rf < 2; ++rf)
#pragma unroll
            for (int p = 0; p < 3; ++p)
                af[rf][p] = *reinterpret_cast<const bf16x8*>(&As[p][rf][lane][0]);
#pragma unroll
        for (int cf = 0; cf < 2; ++cf)
#pragma unroll
            for (int q = 0; q < 3; ++q)
                bfr[cf][q] = *reinterpret_cast<const bf16x8*>(&Bs[q][w * 2 + cf][lane][0]);

#define TERM(p, q) \
        acc[0][0] = __builtin_amdgcn_mfma_f32_16x16x32_bf16(af[0][p], bfr[0][q], acc[0][0], 0, 0, 0); \
        acc[0][1] = __builtin_amdgcn_mfma_f32_16x16x32_bf16(af[0][p], bfr[1][q], acc[0][1], 0, 0, 0); \
        acc[1][0] = __builtin_amdgcn_mfma_f32_16x16x32_bf16(af[1][p], bfr[0][q], acc[1][0], 0, 0, 0); \
        acc[1][1] = __builtin_amdgcn_mfma_f32_16x16x32_bf16(af[1][p], bfr[1][q], acc[1][1], 0, 0, 0);
        TERM(0, 0) TERM(0, 1) TERM(1, 0) TERM(0, 2) TERM(1, 1) TERM(2, 0)
#undef TERM
        if (t < 24) splitA();
    }

    // epilogue: C row = (lane>>4)*4+r, col = lane&15 within each 16x16 frag
    const float* bias = cb ? biasHi : biasLo;
#pragma unroll
    for (int rf = 0; rf < 2; ++rf)
#pragma unroll
        for (int cf = 0; cf < 2; ++cf) {
            int col = colBase + w * 32 + cf * 16 + (lane & 15);
            int cj  = col & 127;
            float bb = bias[cj];
            float vh = cb ? vhi[cj] : 0.f;
#pragma unroll
            for (int r = 0; r < 4; ++r) {
                int row = rowBase + rf * 16 + ((lane >> 4) << 2) + r;
                if (row < N_NODES) {
                    float v = acc[rf][cf][r] + bb;
                    if (cb) v = fmaf(rowmask[row], vh, v);
                    C[(size_t)row * 256 + col] = v;
                }
            }
        }
}

// ---------------------------------------------------------------------------
// fillgemm: blocks [0,GEMMB) = MFMA GEMM (long blocks first, LPT);
//           blocks [GEMMB, GEMMB+EBLOCKS) = CSR fill.
// ---------------------------------------------------------------------------
__global__ __launch_bounds__(256)
void fillgemm_kernel(const int* __restrict__ idxs, const float* __restrict__ ea,
                     const int* __restrict__ eoff, int* __restrict__ fillc,
                     float* __restrict__ eas,
                     const float* __restrict__ A, const u16* __restrict__ Bt,
                     const float* __restrict__ biasLo, const float* __restrict__ biasHi,
                     const float* __restrict__ vhi, const float* __restrict__ rowmask,
                     float* __restrict__ C) {
    int gb = blockIdx.x;
    if (gb < GEMMB) {
        gemm_mfma(A, Bt, biasLo, biasHi, vhi, rowmask, C, gb);
        return;
    }
    int i = (gb - GEMMB) * 256 + threadIdx.x;
    if (i < E_EDGES) {
        int s = idxs[i];
        int p = atomicAdd(&fillc[s], 1);
        eas[eoff[s] + p] = ea[i];
    }
}

// ---------------------------------------------------------------------------
// tail16: R9-verified tail phases at 16 rows/block, grid 625.
// ---------------------------------------------------------------------------
__global__ __launch_bounds__(256)
void tail16_kernel(const float* __restrict__ UX1, const float* __restrict__ w1last,
                   const float* __restrict__ eas, const int* __restrict__ eoff,
                   const int* __restrict__ cnt, const float* __restrict__ maskv,
                   const float* __restrict__ M1, const float* __restrict__ WH,
                   const float* __restrict__ bu2, const float* __restrict__ bx2,
                   const float* __restrict__ v2,
                   const float* __restrict__ w2last, const float* __restrict__ M2,
                   const float* __restrict__ pw, const float* __restrict__ pb,
                   float* __restrict__ UX2, float* __restrict__ proj) {
    __shared__ float Bs[16][264];    // B staging (all GEMM phases)
    __shared__ float mhT[128][18];   // msg means [k][m]
    __shared__ float ts[16][132];    // z1 rows
    __shared__ float ebuf[1024];     // CSR edge window
    int rowBase = blockIdx.x * 16;   // 625*16 = 10000 exact
    int tid = threadIdx.x;
    int tm2 = tid >> 5;              // 0..7 -> rows 2*tm2, 2*tm2+1
    int tn  = tid & 31;

    auto msg_phase = [&](const float* __restrict__ U, const float* __restrict__ wl) {
        int d = tid & 127, sub = tid >> 7;
        float w = wl[d];
        float uu[8], sum[8];
        int es[8], ec[8];
#pragma unroll
        for (int it = 0; it < 8; ++it) {
            int n  = rowBase + it * 2 + sub;
            ec[it] = cnt[n];
            es[it] = eoff[n];
            uu[it] = U[(size_t)n * 256 + d];
            sum[it] = 0.f;
        }
        int ebase = eoff[rowBase];
        int eend  = (rowBase + 16 < N_NODES) ? eoff[rowBase + 16] : E_EDGES;
        for (int w0 = ebase; w0 < eend; w0 += 1024) {
            int wlen = min(1024, eend - w0);
            __syncthreads();
            for (int q = tid; q < wlen; q += 256) ebuf[q] = eas[w0 + q];
            __syncthreads();
#pragma unroll
            for (int it = 0; it < 8; ++it) {
                int lo = max(es[it], w0), hiE = min(es[it] + ec[it], w0 + wlen);
                for (int e = lo; e < hiE; ++e)
                    sum[it] += fmaxf(fmaf(ebuf[e - w0], w, uu[it]), 0.f);
            }
        }
#pragma unroll
        for (int it = 0; it < 8; ++it)
            mhT[d][it * 2 + sub] = (ec[it] > 0) ? sum[it] / (float)ec[it] : 0.f;
    };

    // ===== msg1 =====
    msg_phase(UX1, w1last);
    __syncthreads();

    // ===== phase1: ts = relu(xn1 + mhT @ M1), 16x128 =====
    {
        float acc[2][4] = {};
        for (int k0 = 0; k0 < 128; k0 += 16) {
            int kr = tid >> 4, c8 = (tid & 15) << 3;
            *(float4*)&Bs[kr][c8]     = *(const float4*)(M1 + (size_t)(k0 + kr) * 128 + c8);
            *(float4*)&Bs[kr][c8 + 4] = *(const float4*)(M1 + (size_t)(k0 + kr) * 128 + c8 + 4);
            __syncthreads();
#pragma unroll
            for (int k = 0; k < 16; ++k) {
                float2 a = *(const float2*)&mhT[k0 + k][tm2 << 1];
                float4 b = *(const float4*)&Bs[k][tn << 2];
                acc[0][0] = fmaf(a.x, b.x, acc[0][0]); acc[0][1] = fmaf(a.x, b.y, acc[0][1]);
                acc[0][2] = fmaf(a.x, b.z, acc[0][2]); acc[0][3] = fmaf(a.x, b.w, acc[0][3]);
                acc[1][0] = fmaf(a.y, b.x, acc[1][0]); acc[1][1] = fmaf(a.y, b.y, acc[1][1]);
                acc[1][2] = fmaf(a.y, b.z, acc[1][2]); acc[1][3] = fmaf(a.y, b.w, acc[1][3]);
            }
            __syncthreads();
        }
#pragma unroll
        for (int i = 0; i < 2; ++i) {
            int row = rowBase + (tm2 << 1) + i;
            float4 xn = *(const float4*)(UX1 + (size_t)row * 256 + 128 + (tn << 2));
            float4 o;
            o.x = fmaxf(acc[i][0] + xn.x, 0.f);
            o.y = fmaxf(acc[i][1] + xn.y, 0.f);
            o.z = fmaxf(acc[i][2] + xn.z, 0.f);
            o.w = fmaxf(acc[i][3] + xn.w, 0.f);
            *(float4*)&ts[(tm2 << 1) + i][tn << 2] = o;
        }
    }

    // ===== phase2: UX2 = ts @ WH + bias (+maskv*v2 on hi), 16x256 =====
    {
        float acc[2][8] = {};
        for (int k0 = 0; k0 < 128; k0 += 16) {
            int kr = tid >> 4, c4 = (tid & 15) << 2;
#pragma unroll
            for (int p = 0; p < 4; ++p)
                *(float4*)&Bs[kr][c4 + p * 64] =
                    *(const float4*)(WH + (size_t)(k0 + kr) * 256 + c4 + p * 64);
            __syncthreads();   // also orders ts writes before reads
#pragma unroll
            for (int k = 0; k < 16; ++k) {
                float4 b0 = *(const float4*)&Bs[k][tn << 3];
                float4 b1 = *(const float4*)&Bs[k][(tn << 3) + 4];
                float br[8] = {b0.x, b0.y, b0.z, b0.w, b1.x, b1.y, b1.z, b1.w};
#pragma unroll
                for (int i = 0; i < 2; ++i) {
                    float a = ts[(tm2 << 1) + i][k0 + k];
#pragma unroll
                    for (int j = 0; j < 8; ++j)
                        acc[i][j] = fmaf(a, br[j], acc[i][j]);
                }
            }
            __syncthreads();
        }
        bool hi = tn >= 16;
        const float* bias = hi ? bx2 : bu2;
#pragma unroll
        for (int i = 0; i < 2; ++i) {
            int row = rowBase + (tm2 << 1) + i;
            float rm = maskv[row];
            float4 o0, o1; float* po0 = (float*)&o0; float* po1 = (float*)&o1;
#pragma unroll
            for (int j = 0; j < 4; ++j) {
                int cj0 = ((tn << 3) + j) & 127, cj1 = ((tn << 3) + 4 + j) & 127;
                float q0 = acc[i][j]     + bias[cj0];
                float q1 = acc[i][4 + j] + bias[cj1];
                if (hi) { q0 = fmaf(rm, v2[cj0], q0); q1 = fmaf(rm, v2[cj1], q1); }
                po0[j] = q0; po1[j] = q1;
            }
            float* orow = UX2 + (size_t)row * 256 + (tn << 3);
            *(float4*)orow       = o0;
            *(float4*)(orow + 4) = o1;
        }
    }
    __syncthreads();   // UX2 block-visible (own rows only are read below)

    // ===== msg2 =====
    msg_phase(UX2, w2last);

    // ===== phase4: z2 = relu(xn2 + mhT@M2); proj = z2@pw + pb =====
    {
        float acc[2][4] = {};
        for (int k0 = 0; k0 < 128; k0 += 16) {
            int kr = tid >> 4, c8 = (tid & 15) << 3;
            *(float4*)&Bs[kr][c8]     = *(const float4*)(M2 + (size_t)(k0 + kr) * 128 + c8);
            *(float4*)&Bs[kr][c8 + 4] = *(const float4*)(M2 + (size_t)(k0 + kr) * 128 + c8 + 4);
            __syncthreads();   // also orders msg2's mhT writes
#pragma unroll
            for (int k = 0; k < 16; ++k) {
                float2 a = *(const float2*)&mhT[k0 + k][tm2 << 1];
                float4 b = *(const float4*)&Bs[k][tn << 2];
                acc[0][0] = fmaf(a.x, b.x, acc[0][0]); acc[0][1] = fmaf(a.x, b.y, acc[0][1]);
                acc[0][2] = fmaf(a.x, b.z, acc[0][2]); acc[0][3] = fmaf(a.x, b.w, acc[0][3]);
                acc[1][0] = fmaf(a.y, b.x, acc[1][0]); acc[1][1] = fmaf(a.y, b.y, acc[1][1]);
                acc[1][2] = fmaf(a.y, b.z, acc[1][2]); acc[1][3] = fmaf(a.y, b.w, acc[1][3]);
            }
            __syncthreads();
        }
        float pp0[2], pp1[2];
#pragma unroll
        for (int i = 0; i < 2; ++i) {
            int row = rowBase + (tm2 << 1) + i;
            float4 xn = *(const float4*)(UX2 + (size_t)row * 256 + 128 + (tn << 2));
            float t0 = fmaxf(acc[i][0] + xn.x, 0.f);
            float t1 = fmaxf(acc[i][1] + xn.y, 0.f);
            float t2 = fmaxf(acc[i][2] + xn.z, 0.f);
            float t3 = fmaxf(acc[i][3] + xn.w, 0.f);
            int c = tn << 2;
            pp0[i] = fmaf(t3, pw[2*(c+3)],   fmaf(t2, pw[2*(c+2)],   fmaf(t1, pw[2*(c+1)],   t0 * pw[2*c])));
            pp1[i] = fmaf(t3, pw[2*(c+3)+1], fmaf(t2, pw[2*(c+2)+1], fmaf(t1, pw[2*(c+1)+1], t0 * pw[2*c+1])));
        }
        for (int off = 16; off > 0; off >>= 1) {
            pp0[0] += __shfl_xor(pp0[0], off, 64);
            pp0[1] += __shfl_xor(pp0[1], off, 64);
            pp1[0] += __shfl_xor(pp1[0], off, 64);
            pp1[1] += __shfl_xor(pp1[1], off, 64);
        }
        if (tn == 0) {
#pragma unroll
            for (int i = 0; i < 2; ++i) {
                int row = rowBase + (tm2 << 1) + i;
                proj[2 * row]     = pp0[i] + pb[0];
                proj[2 * row + 1] = pp1[i] + pb[1];
            }
        }
    }
}

__global__ void dist_kernel(const float* __restrict__ proj, const int* __restrict__ idxs,
                            float* __restrict__ out, int e) {
    int i = blockIdx.x * blockDim.x + threadIdx.x;
    if (i >= e) return;
    int n = i / KNB;
    int m = idxs[i];
    float2 pn = *(const float2*)(proj + 2 * n);
    float2 pm = *(const float2*)(proj + 2 * m);
    float dx = pn.x - pm.x;
    float dy = pn.y - pm.y;
    out[i] = dx * dx + dy * dy;
}

// ---------------------------------------------------------------------------
extern "C" void kernel_launch(void* const* d_in, const int* in_sizes, int n_in,
                              void* d_out, int out_size, void* d_ws, size_t ws_size,
                              hipStream_t stream) {
    (void)in_sizes; (void)n_in; (void)out_size; (void)ws_size;
    const float* x    = (const float*)d_in[0];
    const float* eatt = (const float*)d_in[1];
    const int*   idxs = (const int*)d_in[2];
    const float* mw1  = (const float*)d_in[3];
    const float* mb1  = (const float*)d_in[4];
    const float* mw2  = (const float*)d_in[5];
    const float* mb2  = (const float*)d_in[6];
    const float* nw1  = (const float*)d_in[7];
    const float* nb1  = (const float*)d_in[8];
    const float* nw2  = (const float*)d_in[9];
    const float* nb2  = (const float*)d_in[10];
    const float* m2w1 = (const float*)d_in[11];
    const float* m2b1 = (const float*)d_in[12];
    const float* m2w2 = (const float*)d_in[13];
    const float* m2b2 = (const float*)d_in[14];
    const float* n2w1 = (const float*)d_in[15];
    const float* n2b1 = (const float*)d_in[16];
    const float* n2w2 = (const float*)d_in[17];
    const float* n2b2 = (const float*)d_in[18];
    float* out = (float*)d_out;

    float* fws   = (float*)d_ws;
    float* UX1   = fws;                   // 10000*256
    float* UX2   = fws + 2560000;         // 10000*256
    float* proj  = fws + 5120000;         // 10000*2
    float* maskv = fws + 5140000;         // 10000
    float* eas   = fws + 5150016;         // 150000
    float* M1    = fws + 5300016;         // 128*128
    float* M2    = fws + 5316400;         // 128*128
    float* WH    = fws + 5332784;         // 128*256
    float* v1    = fws + 5365552;         // 128
    float* v2    = fws + 5365680;         // 128
    float* bu2   = fws + 5365808;         // 128
    float* bx2   = fws + 5365936;         // 128
    int*   cnt   = (int*)(fws + 5366064);
    int*   fillc = cnt + N_NODES;
    int*   eoff  = fillc + N_NODES;
    // Bt aliases UX2: Bt (1.23 MB) is only live scanfold->fillgemm; UX2 is
    // written (fully) and read only inside tail16, after Bt is dead.
    u16*   Bt    = (u16*)(fws + 2560000); // 3*256*800 bf16 bits

    // L1-2: zero cnt, parallel histogram
    hipMemsetAsync(cnt, 0, N_NODES * sizeof(int), stream);
    count_kernel<<<EBLOCKS, 256, 0, stream>>>(idxs, cnt, E_EDGES);

    // L3: prefix-scan (block 0) + weight folds (1..40) + B bf16x3 split (41..56)
    scanfold_kernel<<<57, 256, 0, stream>>>(mw2, mb2, nw1, nb2, nw2,
                                            m2w1, m2b1, m2w2, m2b2, n2w1, n2b1,
                                            M1, M2, WH, v1, v2, bu2, bx2,
                                            cnt, eoff, maskv, fillc, mw1, Bt);

    // L4: MFMA GEMM (626 blocks, first = LPT) + CSR fill (587 blocks)
    fillgemm_kernel<<<GEMMB + EBLOCKS, 256, 0, stream>>>(
        idxs, eatt, eoff, fillc, eas,
        x, Bt, mb1, nb1, v1, maskv, UX1);

    // L5: tail at 16 rows/block, 625 blocks
    tail16_kernel<<<625, 256, 0, stream>>>(UX1, mw1 + 784 * 128, eas, eoff, cnt, maskv,
                                           M1, WH, bu2, bx2, v2,
                                           m2w1 + 128 * 128, M2,
                                           n2w2, n2b2,
                                           UX2, proj);

    // L6: per-edge squared distances
    dist_kernel<<<EBLOCKS, 256, 0, stream>>>(proj, idxs, out, E_EDGES);
}

// Round 2
// 280.529 us; speedup vs baseline: 1.3616x; 1.3616x over previous
//
#include <hip/hip_runtime.h>

#define N_NODES 10000
#define E_EDGES 150000
#define KNB     15
#define EBLOCKS 587   // ceil(E/256)
#define GEMMB   626   // 313 rowBlks(32 rows) x 2 colBlks(128 cols)

typedef unsigned short u16;
typedef __bf16 bf16x8 __attribute__((ext_vector_type(8)));
typedef float  f32x4  __attribute__((ext_vector_type(4)));

// ---------------------------------------------------------------------------
// Exact-ish bf16x3 split: a ~= hi + mid + lo. hi is RNE bf16 (Veltkamp step is
// exact in fp32), mid/lo truncated. Residual ~2^-25*|a|; dropped cross terms
// (mid*lo etc.) ~2^-26 => fp32-level accuracy with 6 MFMA terms (p+q<=2).
// ---------------------------------------------------------------------------
__device__ __forceinline__ void split3(float a, u16& h, u16& m, u16& l) {
    unsigned u = __float_as_uint(a);
    unsigned t = u + 0x7FFFu + ((u >> 16) & 1u);
    h = (u16)(t >> 16);
    float r1 = a - __uint_as_float(t & 0xFFFF0000u);
    unsigned u1 = __float_as_uint(r1);
    m = (u16)(u1 >> 16);
    float r2 = r1 - __uint_as_float(u1 & 0xFFFF0000u);
    l = (u16)(__float_as_uint(r2) >> 16);
}

// ---------------------------------------------------------------------------
// CSR count: parallel global atomics — NEVER single-block this (R7 lesson).
// ---------------------------------------------------------------------------
__global__ void count_kernel(const int* __restrict__ idxs, int* __restrict__ cnt, int e) {
    int i = blockIdx.x * blockDim.x + threadIdx.x;
    if (i < e) atomicAdd(&cnt[idxs[i]], 1);
}

// ---------------------------------------------------------------------------
// gemm_tile2 (MR=2) — weight-space folds only
// ---------------------------------------------------------------------------
__device__ __forceinline__
void gemm_tile2(const float* __restrict__ A, int K,
                const float* __restrict__ Blo, const float* __restrict__ Bhi, int ldB,
                float* __restrict__ C, int ldC, int M,
                int rowBlk, int colBlk) {
    __shared__ float As2[16][34];
    __shared__ float Bs2[16][64];
    int tid = threadIdx.x;
    int tn  = tid & 15, tm = tid >> 4;
    int arow = tid >> 3, acB = (tid & 7) << 1;
    int brow = tid >> 4, bcol = (tid & 15) << 2;
    int rowBase = rowBlk * 32, colBase = colBlk * 64;

    bool half = (Bhi != nullptr) && (colBase >= 128);
    const float* B = half ? Bhi : Blo;
    int bj = colBase - (half ? 128 : 0) + bcol;

    float2 av; float4 bv;
    auto loadA = [&](int k0, float2& dst) {
        int gr = rowBase + arow;
        if (gr < M) dst = *(const float2*)(A + (size_t)gr * K + k0 + acB);
        else { dst.x = dst.y = 0.f; }
    };
    auto loadB = [&](int k0, float4& dst) {
        dst = *(const float4*)(B + (size_t)(k0 + brow) * ldB + bj);
    };
    loadA(0, av); loadB(0, bv);

    float acc[2][4] = {};
    for (int k0 = 0; k0 < K; k0 += 16) {
        __syncthreads();
        As2[acB + 0][arow] = av.x; As2[acB + 1][arow] = av.y;
        *(float4*)&Bs2[brow][bcol] = bv;
        __syncthreads();
        if (k0 + 16 < K) { loadA(k0 + 16, av); loadB(k0 + 16, bv); }
#pragma unroll
        for (int k = 0; k < 16; ++k) {
            float4 b = *(const float4*)&Bs2[k][tn << 2];
            float2 a = *(const float2*)&As2[k][tm << 1];
            acc[0][0] = fmaf(a.x, b.x, acc[0][0]); acc[0][1] = fmaf(a.x, b.y, acc[0][1]);
            acc[0][2] = fmaf(a.x, b.z, acc[0][2]); acc[0][3] = fmaf(a.x, b.w, acc[0][3]);
            acc[1][0] = fmaf(a.y, b.x, acc[1][0]); acc[1][1] = fmaf(a.y, b.y, acc[1][1]);
            acc[1][2] = fmaf(a.y, b.z, acc[1][2]); acc[1][3] = fmaf(a.y, b.w, acc[1][3]);
        }
    }
#pragma unroll
    for (int i = 0; i < 2; ++i) {
        int row = rowBase + tm * 2 + i;
        if (row >= M) continue;
#pragma unroll
        for (int j = 0; j < 4; ++j)
            C[(size_t)row * ldC + colBase + (tn << 2) + j] = acc[i][j];
    }
}

// ---------------------------------------------------------------------------
// scanfold: block 0 = prefix-scan of cnt; blocks 1..40 = weight folds;
// blocks 41..56 = bf16x3 split + transpose of [mw1|nw1] (rows 0..783, zero-pad
// to 800) into Bt[3][256][800] (bf16 bits, Bt[p][col][k] = B[k][col]).
// ---------------------------------------------------------------------------
__global__ __launch_bounds__(256)
void scanfold_kernel(const float* __restrict__ mw2, const float* __restrict__ mb2,
                     const float* __restrict__ nw1, const float* __restrict__ nb2,
                     const float* __restrict__ nw2,
                     const float* __restrict__ m2w1, const float* __restrict__ m2b1,
                     const float* __restrict__ m2w2, const float* __restrict__ m2b2,
                     const float* __restrict__ n2w1, const float* __restrict__ n2b1,
                     float* __restrict__ M1, float* __restrict__ M2,
                     float* __restrict__ WH,
                     float* __restrict__ v1, float* __restrict__ v2,
                     float* __restrict__ bu2, float* __restrict__ bx2,
                     const int* __restrict__ cnt, int* __restrict__ eoff,
                     float* __restrict__ maskv, int* __restrict__ fillc,
                     const float* __restrict__ mw1, u16* __restrict__ Bt) {
    int b = blockIdx.x;
    if (b >= 41) {
        // ---- bsplit: 16 cols per block, LDS transpose then split3 ----
        __shared__ float Lt[800][17];
        int b2 = b - 41;
        int colBase = b2 * 16;
        const float* S = (colBase < 128) ? mw1 : nw1;
        int sc = colBase & 127;
        int tid = threadIdx.x;
        for (int i = 0; i < 50; ++i) {
            int row = (tid >> 4) + i * 16;
            Lt[row][tid & 15] = (row < 784) ? S[(size_t)row * 128 + sc + (tid & 15)] : 0.f;
        }
        __syncthreads();
        int col = tid >> 4, o = tid & 15;
        size_t dbase = (size_t)(colBase + col) * 800;
        for (int o2 = o; o2 < 100; o2 += 16) {
            u16 hs[8], ms[8], ls[8];
#pragma unroll
            for (int e = 0; e < 8; ++e) split3(Lt[o2 * 8 + e][col], hs[e], ms[e], ls[e]);
            auto pk = [](const u16* s) {
                uint4 v;
                v.x = s[0] | ((unsigned)s[1] << 16); v.y = s[2] | ((unsigned)s[3] << 16);
                v.z = s[4] | ((unsigned)s[5] << 16); v.w = s[6] | ((unsigned)s[7] << 16);
                return v;
            };
            *(uint4*)(Bt +          dbase + o2 * 8) = pk(hs);
            *(uint4*)(Bt + 204800 + dbase + o2 * 8) = pk(ms);
            *(uint4*)(Bt + 409600 + dbase + o2 * 8) = pk(ls);
        }
        return;
    }
    if (b == 0) {
        __shared__ int ssum[256];
        int tid = threadIdx.x;
        const int CH = 40;
        int base = tid * CH;
        int v[CH]; int s = 0;
#pragma unroll
        for (int q = 0; q < CH; ++q) {
            int i = base + q;
            v[q] = (i < N_NODES) ? cnt[i] : 0;
            s += v[q];
        }
        ssum[tid] = s;
        __syncthreads();
        for (int off = 1; off < 256; off <<= 1) {
            int t = (tid >= off) ? ssum[tid - off] : 0;
            __syncthreads();
            ssum[tid] += t;
            __syncthreads();
        }
        int ex = ssum[tid] - s;
#pragma unroll
        for (int q = 0; q < CH; ++q) {
            int i = base + q;
            if (i < N_NODES) {
                eoff[i]  = ex;
                maskv[i] = (v[q] > 0) ? 1.f : 0.f;
                fillc[i] = 0;
                ex += v[q];
            }
        }
        return;
    }
    b -= 1;
    if (b < 8) {
        gemm_tile2(mw2, 784, nw1 + 784 * 128, nullptr, 128, M1, 128, 128, b >> 1, b & 1);
    } else if (b < 16) {
        int t = b - 8;
        gemm_tile2(m2w2, 128, n2w1 + 128 * 128, nullptr, 128, M2, 128, 128, t >> 1, t & 1);
    } else if (b < 32) {
        int t = b - 16;
        gemm_tile2(nw2, 128, m2w1, n2w1, 128, WH, 256, 128, t >> 2, t & 3);
    } else {
        __shared__ float red[256];
        int t  = (b - 32) >> 1;
        int j  = ((b - 32) & 1) * 64 + (threadIdx.x & 63);
        int kq = threadIdx.x >> 6;
        const float* bvec; const float* Bv; const float* add; float* out; int Kv;
        if (t == 0)      { bvec = mb2;  Bv = nw1 + 784 * 128;  add = nullptr; out = v1;  Kv = 784; }
        else if (t == 1) { bvec = m2b2; Bv = n2w1 + 128 * 128; add = nullptr; out = v2;  Kv = 128; }
        else if (t == 2) { bvec = nb2;  Bv = m2w1;             add = m2b1;    out = bu2; Kv = 128; }
        else             { bvec = nb2;  Bv = n2w1;             add = n2b1;    out = bx2; Kv = 128; }
        float acc = 0.f;
        for (int k = kq; k < Kv; k += 4) acc = fmaf(bvec[k], Bv[k * 128 + j], acc);
        red[threadIdx.x] = acc;
        __syncthreads();
        if (threadIdx.x < 64) {
            float tot = red[threadIdx.x] + red[threadIdx.x + 64] +
                        red[threadIdx.x + 128] + red[threadIdx.x + 192];
            out[j] = tot + (add ? add[j] : 0.f);
        }
    }
}

// ---------------------------------------------------------------------------
// MFMA bf16x3 GEMM tile: 32 rows x 128 cols per block, K=784 padded to 800.
// FULLY SCALARIZED (R1 lesson): no lambdas, no local arrays — the R0 version's
// capture-struct/array state was alloca'd to scratch (VGPR=52, WRITE_SIZE
// 194MB of spill traffic, all pipes <6%). Named registers only.
// 6 bf16x3 terms (p+q<=2) per 32-k tile = 24 mfma_f32_16x16x32_bf16/wave.
// LDS fragment-linear ([plane][frag][lane][8]) -> b128 reads conflict-free;
// k-permutation inside a lane-group cancels between A and B fragments.
// ---------------------------------------------------------------------------
#define MF(a, b, c) __builtin_amdgcn_mfma_f32_16x16x32_bf16((a), (b), (c), 0, 0, 0)

__device__ __forceinline__
void gemm_mfma(const float* __restrict__ A, const u16* __restrict__ Bt,
               const float* __restrict__ biasLo, const float* __restrict__ biasHi,
               const float* __restrict__ vhi, const float* __restrict__ rowmask,
               float* __restrict__ C, int gb) {
    __shared__ u16 Bs[3][8][64][8];   // 24 KB  [plane][colfrag][lane][e]
    __shared__ u16 As[3][2][64][8];   //  6 KB  [plane][rowfrag][lane][e]
    const int tid  = threadIdx.x;
    const int lane = tid & 63, w = tid >> 6;
    const int rb = gb >> 1, cb = gb & 1;
    const int rowBase = rb * 32, colBase = cb * 128;

    // ---- A staging coords: thread -> (row, 4-wide k chunk) ----
    const int ar  = tid >> 3;            // 0..31
    const int akc = (tid & 7) << 2;      // 0,4,...,28
    int arow = rowBase + ar; if (arow > N_NODES - 1) arow = N_NODES - 1;
    const float* Ap = A + (size_t)arow * 784;
    const int aL  = (ar & 15) + ((akc >> 3) << 4);   // frag lane
    const int aE  = akc & 4;                         // octet half
    u16* aDst = &As[0][ar >> 4][aL][aE];             // +1024/+2048 per plane

    // ---- B staging: 6 (plane,colfrag) chunks per thread, wid = w*6+j ----
    u16* bBase = &Bs[0][0][lane][0];
#define BDEF(j) \
    const int pl##j = (w * 6 + j) >> 3, cf##j = (w * 6 + j) & 7; \
    const int bofs##j = pl##j * 204800 + (colBase + cf##j * 16 + (lane & 15)) * 800 + ((lane >> 4) << 3); \
    const int bd##j = (pl##j * 8 + cf##j) * 512; \
    uint4 bv##j;
    BDEF(0) BDEF(1) BDEF(2) BDEF(3) BDEF(4) BDEF(5)
#undef BDEF

    float4 av;
    ushort4 a3h, a3m, a3l;

#define ALOAD(k0) { int kk = akc + (k0); if (kk >= 784) kk = 0; \
                    av = *(const float4*)(Ap + kk); }
#define BLOADALL(k0) \
    bv0 = *(const uint4*)(Bt + bofs0 + (k0)); \
    bv1 = *(const uint4*)(Bt + bofs1 + (k0)); \
    bv2 = *(const uint4*)(Bt + bofs2 + (k0)); \
    bv3 = *(const uint4*)(Bt + bofs3 + (k0)); \
    bv4 = *(const uint4*)(Bt + bofs4 + (k0)); \
    bv5 = *(const uint4*)(Bt + bofs5 + (k0));
#define ASPLIT() { u16 h, m, l; \
    split3(av.x, h, m, l); a3h.x = h; a3m.x = m; a3l.x = l; \
    split3(av.y, h, m, l); a3h.y = h; a3m.y = m; a3l.y = l; \
    split3(av.z, h, m, l); a3h.z = h; a3m.z = m; a3l.z = l; \
    split3(av.w, h, m, l); a3h.w = h; a3m.w = m; a3l.w = l; }

    f32x4 acc00 = {0.f, 0.f, 0.f, 0.f};
    f32x4 acc01 = acc00, acc10 = acc00, acc11 = acc00;

    ALOAD(0) BLOADALL(0) ASPLIT()

    // fragment read bases (u16 units)
    const u16* aFr = &As[0][0][lane][0];     // +512/rf, +1024/plane
    const u16* bFr = &Bs[0][w * 2][lane][0]; // +512/cf, +4096/plane

    for (int t = 0; t < 25; ++t) {
        __syncthreads();
        *(ushort4*)(aDst)        = a3h;
        *(ushort4*)(aDst + 1024) = a3m;
        *(ushort4*)(aDst + 2048) = a3l;
        *(uint4*)(bBase + bd0) = bv0;
        *(uint4*)(bBase + bd1) = bv1;
        *(uint4*)(bBase + bd2) = bv2;
        *(uint4*)(bBase + bd3) = bv3;
        *(uint4*)(bBase + bd4) = bv4;
        *(uint4*)(bBase + bd5) = bv5;
        __syncthreads();
        const int kn = (t + 1) << 5;
        if (t < 24) { ALOAD(kn) BLOADALL(kn) }

        bf16x8 a0h = *(const bf16x8*)(aFr);
        bf16x8 a1h = *(const bf16x8*)(aFr + 512);
        bf16x8 a0m = *(const bf16x8*)(aFr + 1024);
        bf16x8 a1m = *(const bf16x8*)(aFr + 1536);
        bf16x8 a0l = *(const bf16x8*)(aFr + 2048);
        bf16x8 a1l = *(const bf16x8*)(aFr + 2560);

        // q=0 (B hi): p = 0,1,2
        bf16x8 bb0 = *(const bf16x8*)(bFr);
        bf16x8 bb1 = *(const bf16x8*)(bFr + 512);
        acc00 = MF(a0h, bb0, acc00); acc01 = MF(a0h, bb1, acc01);
        acc10 = MF(a1h, bb0, acc10); acc11 = MF(a1h, bb1, acc11);
        acc00 = MF(a0m, bb0, acc00); acc01 = MF(a0m, bb1, acc01);
        acc10 = MF(a1m, bb0, acc10); acc11 = MF(a1m, bb1, acc11);
        acc00 = MF(a0l, bb0, acc00); acc01 = MF(a0l, bb1, acc01);
        acc10 = MF(a1l, bb0, acc10); acc11 = MF(a1l, bb1, acc11);
        // q=1 (B mid): p = 0,1
        bf16x8 bc0 = *(const bf16x8*)(bFr + 4096);
        bf16x8 bc1 = *(const bf16x8*)(bFr + 4608);
        acc00 = MF(a0h, bc0, acc00); acc01 = MF(a0h, bc1, acc01);
        acc10 = MF(a1h, bc0, acc10); acc11 = MF(a1h, bc1, acc11);
        acc00 = MF(a0m, bc0, acc00); acc01 = MF(a0m, bc1, acc01);
        acc10 = MF(a1m, bc0, acc10); acc11 = MF(a1m, bc1, acc11);
        // q=2 (B lo): p = 0
        bf16x8 bdq0 = *(const bf16x8*)(bFr + 8192);
        bf16x8 bdq1 = *(const bf16x8*)(bFr + 8704);
        acc00 = MF(a0h, bdq0, acc00); acc01 = MF(a0h, bdq1, acc01);
        acc10 = MF(a1h, bdq0, acc10); acc11 = MF(a1h, bdq1, acc11);

        if (t < 24) ASPLIT()
    }
#undef ALOAD
#undef BLOADALL
#undef ASPLIT

    // epilogue: C row = (lane>>4)*4+r, col = lane&15 within each 16x16 frag
    const float* bias = cb ? biasHi : biasLo;
#define EPI(rf, cf, ACC) { \
        const int col = colBase + w * 32 + (cf) * 16 + (lane & 15); \
        const int cj  = col & 127; \
        const float bb = bias[cj]; \
        const float vh = cb ? vhi[cj] : 0.f; \
        const int rbase = rowBase + (rf) * 16 + ((lane >> 4) << 2); \
        _Pragma("unroll") \
        for (int r = 0; r < 4; ++r) { \
            int row = rbase + r; \
            if (row < N_NODES) { \
                float v = ACC[r] + bb; \
                if (cb) v = fmaf(rowmask[row], vh, v); \
                C[(size_t)row * 256 + col] = v; \
            } } }
    EPI(0, 0, acc00) EPI(0, 1, acc01) EPI(1, 0, acc10) EPI(1, 1, acc11)
#undef EPI
}

// ---------------------------------------------------------------------------
// fillgemm: blocks [0,GEMMB) = MFMA GEMM (long blocks first, LPT);
//           blocks [GEMMB, GEMMB+EBLOCKS) = CSR fill.
// ---------------------------------------------------------------------------
__global__ __launch_bounds__(256)
void fillgemm_kernel(const int* __restrict__ idxs, const float* __restrict__ ea,
                     const int* __restrict__ eoff, int* __restrict__ fillc,
                     float* __restrict__ eas,
                     const float* __restrict__ A, const u16* __restrict__ Bt,
                     const float* __restrict__ biasLo, const float* __restrict__ biasHi,
                     const float* __restrict__ vhi, const float* __restrict__ rowmask,
                     float* __restrict__ C) {
    int gb = blockIdx.x;
    if (gb < GEMMB) {
        gemm_mfma(A, Bt, biasLo, biasHi, vhi, rowmask, C, gb);
        return;
    }
    int i = (gb - GEMMB) * 256 + threadIdx.x;
    if (i < E_EDGES) {
        int s = idxs[i];
        int p = atomicAdd(&fillc[s], 1);
        eas[eoff[s] + p] = ea[i];
    }
}

// ---------------------------------------------------------------------------
// tail16: R9-verified tail phases at 16 rows/block, grid 625.
// ---------------------------------------------------------------------------
__global__ __launch_bounds__(256)
void tail16_kernel(const float* __restrict__ UX1, const float* __restrict__ w1last,
                   const float* __restrict__ eas, const int* __restrict__ eoff,
                   const int* __restrict__ cnt, const float* __restrict__ maskv,
                   const float* __restrict__ M1, const float* __restrict__ WH,
                   const float* __restrict__ bu2, const float* __restrict__ bx2,
                   const float* __restrict__ v2,
                   const float* __restrict__ w2last, const float* __restrict__ M2,
                   const float* __restrict__ pw, const float* __restrict__ pb,
                   float* __restrict__ UX2, float* __restrict__ proj) {
    __shared__ float Bs[16][264];    // B staging (all GEMM phases)
    __shared__ float mhT[128][18];   // msg means [k][m]
    __shared__ float ts[16][132];    // z1 rows
    __shared__ float ebuf[1024];     // CSR edge window
    int rowBase = blockIdx.x * 16;   // 625*16 = 10000 exact
    int tid = threadIdx.x;
    int tm2 = tid >> 5;              // 0..7 -> rows 2*tm2, 2*tm2+1
    int tn  = tid & 31;

    auto msg_phase = [&](const float* __restrict__ U, const float* __restrict__ wl) {
        int d = tid & 127, sub = tid >> 7;
        float w = wl[d];
        float uu[8], sum[8];
        int es[8], ec[8];
#pragma unroll
        for (int it = 0; it < 8; ++it) {
            int n  = rowBase + it * 2 + sub;
            ec[it] = cnt[n];
            es[it] = eoff[n];
            uu[it] = U[(size_t)n * 256 + d];
            sum[it] = 0.f;
        }
        int ebase = eoff[rowBase];
        int eend  = (rowBase + 16 < N_NODES) ? eoff[rowBase + 16] : E_EDGES;
        for (int w0 = ebase; w0 < eend; w0 += 1024) {
            int wlen = min(1024, eend - w0);
            __syncthreads();
            for (int q = tid; q < wlen; q += 256) ebuf[q] = eas[w0 + q];
            __syncthreads();
#pragma unroll
            for (int it = 0; it < 8; ++it) {
                int lo = max(es[it], w0), hiE = min(es[it] + ec[it], w0 + wlen);
                for (int e = lo; e < hiE; ++e)
                    sum[it] += fmaxf(fmaf(ebuf[e - w0], w, uu[it]), 0.f);
            }
        }
#pragma unroll
        for (int it = 0; it < 8; ++it)
            mhT[d][it * 2 + sub] = (ec[it] > 0) ? sum[it] / (float)ec[it] : 0.f;
    };

    // ===== msg1 =====
    msg_phase(UX1, w1last);
    __syncthreads();

    // ===== phase1: ts = relu(xn1 + mhT @ M1), 16x128 =====
    {
        float acc[2][4] = {};
        for (int k0 = 0; k0 < 128; k0 += 16) {
            int kr = tid >> 4, c8 = (tid & 15) << 3;
            *(float4*)&Bs[kr][c8]     = *(const float4*)(M1 + (size_t)(k0 + kr) * 128 + c8);
            *(float4*)&Bs[kr][c8 + 4] = *(const float4*)(M1 + (size_t)(k0 + kr) * 128 + c8 + 4);
            __syncthreads();
#pragma unroll
            for (int k = 0; k < 16; ++k) {
                float2 a = *(const float2*)&mhT[k0 + k][tm2 << 1];
                float4 b = *(const float4*)&Bs[k][tn << 2];
                acc[0][0] = fmaf(a.x, b.x, acc[0][0]); acc[0][1] = fmaf(a.x, b.y, acc[0][1]);
                acc[0][2] = fmaf(a.x, b.z, acc[0][2]); acc[0][3] = fmaf(a.x, b.w, acc[0][3]);
                acc[1][0] = fmaf(a.y, b.x, acc[1][0]); acc[1][1] = fmaf(a.y, b.y, acc[1][1]);
                acc[1][2] = fmaf(a.y, b.z, acc[1][2]); acc[1][3] = fmaf(a.y, b.w, acc[1][3]);
            }
            __syncthreads();
        }
#pragma unroll
        for (int i = 0; i < 2; ++i) {
            int row = rowBase + (tm2 << 1) + i;
            float4 xn = *(const float4*)(UX1 + (size_t)row * 256 + 128 + (tn << 2));
            float4 o;
            o.x = fmaxf(acc[i][0] + xn.x, 0.f);
            o.y = fmaxf(acc[i][1] + xn.y, 0.f);
            o.z = fmaxf(acc[i][2] + xn.z, 0.f);
            o.w = fmaxf(acc[i][3] + xn.w, 0.f);
            *(float4*)&ts[(tm2 << 1) + i][tn << 2] = o;
        }
    }

    // ===== phase2: UX2 = ts @ WH + bias (+maskv*v2 on hi), 16x256 =====
    {
        float acc[2][8] = {};
        for (int k0 = 0; k0 < 128; k0 += 16) {
            int kr = tid >> 4, c4 = (tid & 15) << 2;
#pragma unroll
            for (int p = 0; p < 4; ++p)
                *(float4*)&Bs[kr][c4 + p * 64] =
                    *(const float4*)(WH + (size_t)(k0 + kr) * 256 + c4 + p * 64);
            __syncthreads();   // also orders ts writes before reads
#pragma unroll
            for (int k = 0; k < 16; ++k) {
                float4 b0 = *(const float4*)&Bs[k][tn << 3];
                float4 b1 = *(const float4*)&Bs[k][(tn << 3) + 4];
                float br[8] = {b0.x, b0.y, b0.z, b0.w, b1.x, b1.y, b1.z, b1.w};
#pragma unroll
                for (int i = 0; i < 2; ++i) {
                    float a = ts[(tm2 << 1) + i][k0 + k];
#pragma unroll
                    for (int j = 0; j < 8; ++j)
                        acc[i][j] = fmaf(a, br[j], acc[i][j]);
                }
            }
            __syncthreads();
        }
        bool hi = tn >= 16;
        const float* bias = hi ? bx2 : bu2;
#pragma unroll
        for (int i = 0; i < 2; ++i) {
            int row = rowBase + (tm2 << 1) + i;
            float rm = maskv[row];
            float4 o0, o1; float* po0 = (float*)&o0; float* po1 = (float*)&o1;
#pragma unroll
            for (int j = 0; j < 4; ++j) {
                int cj0 = ((tn << 3) + j) & 127, cj1 = ((tn << 3) + 4 + j) & 127;
                float q0 = acc[i][j]     + bias[cj0];
                float q1 = acc[i][4 + j] + bias[cj1];
                if (hi) { q0 = fmaf(rm, v2[cj0], q0); q1 = fmaf(rm, v2[cj1], q1); }
                po0[j] = q0; po1[j] = q1;
            }
            float* orow = UX2 + (size_t)row * 256 + (tn << 3);
            *(float4*)orow       = o0;
            *(float4*)(orow + 4) = o1;
        }
    }
    __syncthreads();   // UX2 block-visible (own rows only are read below)

    // ===== msg2 =====
    msg_phase(UX2, w2last);

    // ===== phase4: z2 = relu(xn2 + mhT@M2); proj = z2@pw + pb =====
    {
        float acc[2][4] = {};
        for (int k0 = 0; k0 < 128; k0 += 16) {
            int kr = tid >> 4, c8 = (tid & 15) << 3;
            *(float4*)&Bs[kr][c8]     = *(const float4*)(M2 + (size_t)(k0 + kr) * 128 + c8);
            *(float4*)&Bs[kr][c8 + 4] = *(const float4*)(M2 + (size_t)(k0 + kr) * 128 + c8 + 4);
            __syncthreads();   // also orders msg2's mhT writes
#pragma unroll
            for (int k = 0; k < 16; ++k) {
                float2 a = *(const float2*)&mhT[k0 + k][tm2 << 1];
                float4 b = *(const float4*)&Bs[k][tn << 2];
                acc[0][0] = fmaf(a.x, b.x, acc[0][0]); acc[0][1] = fmaf(a.x, b.y, acc[0][1]);
                acc[0][2] = fmaf(a.x, b.z, acc[0][2]); acc[0][3] = fmaf(a.x, b.w, acc[0][3]);
                acc[1][0] = fmaf(a.y, b.x, acc[1][0]); acc[1][1] = fmaf(a.y, b.y, acc[1][1]);
                acc[1][2] = fmaf(a.y, b.z, acc[1][2]); acc[1][3] = fmaf(a.y, b.w, acc[1][3]);
            }
            __syncthreads();
        }
        float pp0[2], pp1[2];
#pragma unroll
        for (int i = 0; i < 2; ++i) {
            int row = rowBase + (tm2 << 1) + i;
            float4 xn = *(const float4*)(UX2 + (size_t)row * 256 + 128 + (tn << 2));
            float t0 = fmaxf(acc[i][0] + xn.x, 0.f);
            float t1 = fmaxf(acc[i][1] + xn.y, 0.f);
            float t2 = fmaxf(acc[i][2] + xn.z, 0.f);
            float t3 = fmaxf(acc[i][3] + xn.w, 0.f);
            int c = tn << 2;
            pp0[i] = fmaf(t3, pw[2*(c+3)],   fmaf(t2, pw[2*(c+2)],   fmaf(t1, pw[2*(c+1)],   t0 * pw[2*c])));
            pp1[i] = fmaf(t3, pw[2*(c+3)+1], fmaf(t2, pw[2*(c+2)+1], fmaf(t1, pw[2*(c+1)+1], t0 * pw[2*c+1])));
        }
        for (int off = 16; off > 0; off >>= 1) {
            pp0[0] += __shfl_xor(pp0[0], off, 64);
            pp0[1] += __shfl_xor(pp0[1], off, 64);
            pp1[0] += __shfl_xor(pp1[0], off, 64);
            pp1[1] += __shfl_xor(pp1[1], off, 64);
        }
        if (tn == 0) {
#pragma unroll
            for (int i = 0; i < 2; ++i) {
                int row = rowBase + (tm2 << 1) + i;
                proj[2 * row]     = pp0[i] + pb[0];
                proj[2 * row + 1] = pp1[i] + pb[1];
            }
        }
    }
}

__global__ void dist_kernel(const float* __restrict__ proj, const int* __restrict__ idxs,
                            float* __restrict__ out, int e) {
    int i = blockIdx.x * blockDim.x + threadIdx.x;
    if (i >= e) return;
    int n = i / KNB;
    int m = idxs[i];
    float2 pn = *(const float2*)(proj + 2 * n);
    float2 pm = *(const float2*)(proj + 2 * m);
    float dx = pn.x - pm.x;
    float dy = pn.y - pm.y;
    out[i] = dx * dx + dy * dy;
}

// ---------------------------------------------------------------------------
extern "C" void kernel_launch(void* const* d_in, const int* in_sizes, int n_in,
                              void* d_out, int out_size, void* d_ws, size_t ws_size,
                              hipStream_t stream) {
    (void)in_sizes; (void)n_in; (void)out_size; (void)ws_size;
    const float* x    = (const float*)d_in[0];
    const float* eatt = (const float*)d_in[1];
    const int*   idxs = (const int*)d_in[2];
    const float* mw1  = (const float*)d_in[3];
    const float* mb1  = (const float*)d_in[4];
    const float* mw2  = (const float*)d_in[5];
    const float* mb2  = (const float*)d_in[6];
    const float* nw1  = (const float*)d_in[7];
    const float* nb1  = (const float*)d_in[8];
    const float* nw2  = (const float*)d_in[9];
    const float* nb2  = (const float*)d_in[10];
    const float* m2w1 = (const float*)d_in[11];
    const float* m2b1 = (const float*)d_in[12];
    const float* m2w2 = (const float*)d_in[13];
    const float* m2b2 = (const float*)d_in[14];
    const float* n2w1 = (const float*)d_in[15];
    const float* n2b1 = (const float*)d_in[16];
    const float* n2w2 = (const float*)d_in[17];
    const float* n2b2 = (const float*)d_in[18];
    float* out = (float*)d_out;

    float* fws   = (float*)d_ws;
    float* UX1   = fws;                   // 10000*256
    float* UX2   = fws + 2560000;         // 10000*256
    float* proj  = fws + 5120000;         // 10000*2
    float* maskv = fws + 5140000;         // 10000
    float* eas   = fws + 5150016;         // 150000
    float* M1    = fws + 5300016;         // 128*128
    float* M2    = fws + 5316400;         // 128*128
    float* WH    = fws + 5332784;         // 128*256
    float* v1    = fws + 5365552;         // 128
    float* v2    = fws + 5365680;         // 128
    float* bu2   = fws + 5365808;         // 128
    float* bx2   = fws + 5365936;         // 128
    int*   cnt   = (int*)(fws + 5366064);
    int*   fillc = cnt + N_NODES;
    int*   eoff  = fillc + N_NODES;
    // Bt aliases UX2: Bt (1.23 MB) is only live scanfold->fillgemm; UX2 is
    // written (fully) and read only inside tail16, after Bt is dead.
    u16*   Bt    = (u16*)(fws + 2560000); // 3*256*800 bf16 bits

    // L1-2: zero cnt, parallel histogram
    hipMemsetAsync(cnt, 0, N_NODES * sizeof(int), stream);
    count_kernel<<<EBLOCKS, 256, 0, stream>>>(idxs, cnt, E_EDGES);

    // L3: prefix-scan (block 0) + weight folds (1..40) + B bf16x3 split (41..56)
    scanfold_kernel<<<57, 256, 0, stream>>>(mw2, mb2, nw1, nb2, nw2,
                                            m2w1, m2b1, m2w2, m2b2, n2w1, n2b1,
                                            M1, M2, WH, v1, v2, bu2, bx2,
                                            cnt, eoff, maskv, fillc, mw1, Bt);

    // L4: MFMA GEMM (626 blocks, first = LPT) + CSR fill (587 blocks)
    fillgemm_kernel<<<GEMMB + EBLOCKS, 256, 0, stream>>>(
        idxs, eatt, eoff, fillc, eas,
        x, Bt, mb1, nb1, v1, maskv, UX1);

    // L5: tail at 16 rows/block, 625 blocks
    tail16_kernel<<<625, 256, 0, stream>>>(UX1, mw1 + 784 * 128, eas, eoff, cnt, maskv,
                                           M1, WH, bu2, bx2, v2,
                                           m2w1 + 128 * 128, M2,
                                           n2w2, n2b2,
                                           UX2, proj);

    // L6: per-edge squared distances
    dist_kernel<<<EBLOCKS, 256, 0, stream>>>(proj, idxs, out, E_EDGES);
}

// Round 3
// 252.044 us; speedup vs baseline: 1.5155x; 1.1130x over previous
//
#include <hip/hip_runtime.h>

#define N_NODES 10000
#define E_EDGES 150000
#define KNB     15
#define EBLOCKS 587   // ceil(E/256)
#define GEMMB   626   // 313 rowBlks(32 rows) x 2 colBlks(128 cols)

typedef unsigned short u16;
typedef __bf16 bf16x8 __attribute__((ext_vector_type(8)));
typedef float  f32x4  __attribute__((ext_vector_type(4)));

// ---------------------------------------------------------------------------
// Exact-ish bf16x3 split: a ~= hi + mid + lo. hi is RNE bf16 (Veltkamp step is
// exact in fp32), mid/lo truncated. Residual ~2^-25*|a|; dropped cross terms
// (mid*lo etc.) ~2^-26 => fp32-level accuracy with 6 MFMA terms (p+q<=2).
// ---------------------------------------------------------------------------
__device__ __forceinline__ void split3(float a, u16& h, u16& m, u16& l) {
    unsigned u = __float_as_uint(a);
    unsigned t = u + 0x7FFFu + ((u >> 16) & 1u);
    h = (u16)(t >> 16);
    float r1 = a - __uint_as_float(t & 0xFFFF0000u);
    unsigned u1 = __float_as_uint(r1);
    m = (u16)(u1 >> 16);
    float r2 = r1 - __uint_as_float(u1 & 0xFFFF0000u);
    l = (u16)(__float_as_uint(r2) >> 16);
}

// ---------------------------------------------------------------------------
// CSR count: parallel global atomics — NEVER single-block this (R7 lesson).
// ---------------------------------------------------------------------------
__global__ void count_kernel(const int* __restrict__ idxs, int* __restrict__ cnt, int e) {
    int i = blockIdx.x * blockDim.x + threadIdx.x;
    if (i < e) atomicAdd(&cnt[idxs[i]], 1);
}

// ---------------------------------------------------------------------------
// gemm_tile2 (MR=2) — weight-space folds only
// ---------------------------------------------------------------------------
__device__ __forceinline__
void gemm_tile2(const float* __restrict__ A, int K,
                const float* __restrict__ Blo, const float* __restrict__ Bhi, int ldB,
                float* __restrict__ C, int ldC, int M,
                int rowBlk, int colBlk) {
    __shared__ float As2[16][34];
    __shared__ float Bs2[16][64];
    int tid = threadIdx.x;
    int tn  = tid & 15, tm = tid >> 4;
    int arow = tid >> 3, acB = (tid & 7) << 1;
    int brow = tid >> 4, bcol = (tid & 15) << 2;
    int rowBase = rowBlk * 32, colBase = colBlk * 64;

    bool half = (Bhi != nullptr) && (colBase >= 128);
    const float* B = half ? Bhi : Blo;
    int bj = colBase - (half ? 128 : 0) + bcol;

    float2 av; float4 bv;
    auto loadA = [&](int k0, float2& dst) {
        int gr = rowBase + arow;
        if (gr < M) dst = *(const float2*)(A + (size_t)gr * K + k0 + acB);
        else { dst.x = dst.y = 0.f; }
    };
    auto loadB = [&](int k0, float4& dst) {
        dst = *(const float4*)(B + (size_t)(k0 + brow) * ldB + bj);
    };
    loadA(0, av); loadB(0, bv);

    float acc[2][4] = {};
    for (int k0 = 0; k0 < K; k0 += 16) {
        __syncthreads();
        As2[acB + 0][arow] = av.x; As2[acB + 1][arow] = av.y;
        *(float4*)&Bs2[brow][bcol] = bv;
        __syncthreads();
        if (k0 + 16 < K) { loadA(k0 + 16, av); loadB(k0 + 16, bv); }
#pragma unroll
        for (int k = 0; k < 16; ++k) {
            float4 b = *(const float4*)&Bs2[k][tn << 2];
            float2 a = *(const float2*)&As2[k][tm << 1];
            acc[0][0] = fmaf(a.x, b.x, acc[0][0]); acc[0][1] = fmaf(a.x, b.y, acc[0][1]);
            acc[0][2] = fmaf(a.x, b.z, acc[0][2]); acc[0][3] = fmaf(a.x, b.w, acc[0][3]);
            acc[1][0] = fmaf(a.y, b.x, acc[1][0]); acc[1][1] = fmaf(a.y, b.y, acc[1][1]);
            acc[1][2] = fmaf(a.y, b.z, acc[1][2]); acc[1][3] = fmaf(a.y, b.w, acc[1][3]);
        }
    }
#pragma unroll
    for (int i = 0; i < 2; ++i) {
        int row = rowBase + tm * 2 + i;
        if (row >= M) continue;
#pragma unroll
        for (int j = 0; j < 4; ++j)
            C[(size_t)row * ldC + colBase + (tn << 2) + j] = acc[i][j];
    }
}

// ---------------------------------------------------------------------------
// scanfold: block 0 = prefix-scan of cnt; blocks 1..40 = weight folds;
// blocks 41..56 = bf16x3 split + transpose of [mw1|nw1] (rows 0..783, zero-pad
// to 800) into Bt[3][256][800] (bf16 bits, Bt[p][col][k] = B[k][col]).
// ---------------------------------------------------------------------------
__global__ __launch_bounds__(256)
void scanfold_kernel(const float* __restrict__ mw2, const float* __restrict__ mb2,
                     const float* __restrict__ nw1, const float* __restrict__ nb2,
                     const float* __restrict__ nw2,
                     const float* __restrict__ m2w1, const float* __restrict__ m2b1,
                     const float* __restrict__ m2w2, const float* __restrict__ m2b2,
                     const float* __restrict__ n2w1, const float* __restrict__ n2b1,
                     float* __restrict__ M1, float* __restrict__ M2,
                     float* __restrict__ WH,
                     float* __restrict__ v1, float* __restrict__ v2,
                     float* __restrict__ bu2, float* __restrict__ bx2,
                     const int* __restrict__ cnt, int* __restrict__ eoff,
                     float* __restrict__ maskv, int* __restrict__ fillc,
                     const float* __restrict__ mw1, u16* __restrict__ Bt) {
    int b = blockIdx.x;
    if (b >= 41) {
        // ---- bsplit: 16 cols per block, LDS transpose then split3 ----
        __shared__ float Lt[800][17];
        int b2 = b - 41;
        int colBase = b2 * 16;
        const float* S = (colBase < 128) ? mw1 : nw1;
        int sc = colBase & 127;
        int tid = threadIdx.x;
        for (int i = 0; i < 50; ++i) {
            int row = (tid >> 4) + i * 16;
            Lt[row][tid & 15] = (row < 784) ? S[(size_t)row * 128 + sc + (tid & 15)] : 0.f;
        }
        __syncthreads();
        int col = tid >> 4, o = tid & 15;
        size_t dbase = (size_t)(colBase + col) * 800;
        for (int o2 = o; o2 < 100; o2 += 16) {
            u16 hs[8], ms[8], ls[8];
#pragma unroll
            for (int e = 0; e < 8; ++e) split3(Lt[o2 * 8 + e][col], hs[e], ms[e], ls[e]);
            auto pk = [](const u16* s) {
                uint4 v;
                v.x = s[0] | ((unsigned)s[1] << 16); v.y = s[2] | ((unsigned)s[3] << 16);
                v.z = s[4] | ((unsigned)s[5] << 16); v.w = s[6] | ((unsigned)s[7] << 16);
                return v;
            };
            *(uint4*)(Bt +          dbase + o2 * 8) = pk(hs);
            *(uint4*)(Bt + 204800 + dbase + o2 * 8) = pk(ms);
            *(uint4*)(Bt + 409600 + dbase + o2 * 8) = pk(ls);
        }
        return;
    }
    if (b == 0) {
        __shared__ int ssum[256];
        int tid = threadIdx.x;
        const int CH = 40;
        int base = tid * CH;
        int v[CH]; int s = 0;
#pragma unroll
        for (int q = 0; q < CH; ++q) {
            int i = base + q;
            v[q] = (i < N_NODES) ? cnt[i] : 0;
            s += v[q];
        }
        ssum[tid] = s;
        __syncthreads();
        for (int off = 1; off < 256; off <<= 1) {
            int t = (tid >= off) ? ssum[tid - off] : 0;
            __syncthreads();
            ssum[tid] += t;
            __syncthreads();
        }
        int ex = ssum[tid] - s;
#pragma unroll
        for (int q = 0; q < CH; ++q) {
            int i = base + q;
            if (i < N_NODES) {
                eoff[i]  = ex;
                maskv[i] = (v[q] > 0) ? 1.f : 0.f;
                fillc[i] = 0;
                ex += v[q];
            }
        }
        return;
    }
    b -= 1;
    if (b < 8) {
        gemm_tile2(mw2, 784, nw1 + 784 * 128, nullptr, 128, M1, 128, 128, b >> 1, b & 1);
    } else if (b < 16) {
        int t = b - 8;
        gemm_tile2(m2w2, 128, n2w1 + 128 * 128, nullptr, 128, M2, 128, 128, t >> 1, t & 1);
    } else if (b < 32) {
        int t = b - 16;
        gemm_tile2(nw2, 128, m2w1, n2w1, 128, WH, 256, 128, t >> 2, t & 3);
    } else {
        __shared__ float red[256];
        int t  = (b - 32) >> 1;
        int j  = ((b - 32) & 1) * 64 + (threadIdx.x & 63);
        int kq = threadIdx.x >> 6;
        const float* bvec; const float* Bv; const float* add; float* out; int Kv;
        if (t == 0)      { bvec = mb2;  Bv = nw1 + 784 * 128;  add = nullptr; out = v1;  Kv = 784; }
        else if (t == 1) { bvec = m2b2; Bv = n2w1 + 128 * 128; add = nullptr; out = v2;  Kv = 128; }
        else if (t == 2) { bvec = nb2;  Bv = m2w1;             add = m2b1;    out = bu2; Kv = 128; }
        else             { bvec = nb2;  Bv = n2w1;             add = n2b1;    out = bx2; Kv = 128; }
        float acc = 0.f;
        for (int k = kq; k < Kv; k += 4) acc = fmaf(bvec[k], Bv[k * 128 + j], acc);
        red[threadIdx.x] = acc;
        __syncthreads();
        if (threadIdx.x < 64) {
            float tot = red[threadIdx.x] + red[threadIdx.x + 64] +
                        red[threadIdx.x + 128] + red[threadIdx.x + 192];
            out[j] = tot + (add ? add[j] : 0.f);
        }
    }
}

// ---------------------------------------------------------------------------
// MFMA bf16x3 GEMM tile: 32 rows x 128 cols per block, K=784 padded to 800.
// FULLY SCALARIZED (R1 lesson): named registers only — array/lambda state
// alloca'd to scratch (VGPR=52, 194MB spill traffic, all pipes <6%).
// ---------------------------------------------------------------------------
#define MF(a, b, c) __builtin_amdgcn_mfma_f32_16x16x32_bf16((a), (b), (c), 0, 0, 0)

__device__ __forceinline__
void gemm_mfma(const float* __restrict__ A, const u16* __restrict__ Bt,
               const float* __restrict__ biasLo, const float* __restrict__ biasHi,
               const float* __restrict__ vhi, const float* __restrict__ rowmask,
               float* __restrict__ C, int gb) {
    __shared__ u16 Bs[3][8][64][8];   // 24 KB  [plane][colfrag][lane][e]
    __shared__ u16 As[3][2][64][8];   //  6 KB  [plane][rowfrag][lane][e]
    const int tid  = threadIdx.x;
    const int lane = tid & 63, w = tid >> 6;
    const int rb = gb >> 1, cb = gb & 1;
    const int rowBase = rb * 32, colBase = cb * 128;

    // ---- A staging coords: thread -> (row, 4-wide k chunk) ----
    const int ar  = tid >> 3;            // 0..31
    const int akc = (tid & 7) << 2;      // 0,4,...,28
    int arow = rowBase + ar; if (arow > N_NODES - 1) arow = N_NODES - 1;
    const float* Ap = A + (size_t)arow * 784;
    const int aL  = (ar & 15) + ((akc >> 3) << 4);   // frag lane
    const int aE  = akc & 4;                         // octet half
    u16* aDst = &As[0][ar >> 4][aL][aE];             // +1024/+2048 per plane

    // ---- B staging: 6 (plane,colfrag) chunks per thread, wid = w*6+j ----
    u16* bBase = &Bs[0][0][lane][0];
#define BDEF(j) \
    const int pl##j = (w * 6 + j) >> 3, cf##j = (w * 6 + j) & 7; \
    const int bofs##j = pl##j * 204800 + (colBase + cf##j * 16 + (lane & 15)) * 800 + ((lane >> 4) << 3); \
    const int bd##j = (pl##j * 8 + cf##j) * 512; \
    uint4 bv##j;
    BDEF(0) BDEF(1) BDEF(2) BDEF(3) BDEF(4) BDEF(5)
#undef BDEF

    float4 av;
    ushort4 a3h, a3m, a3l;

#define ALOAD(k0) { int kk = akc + (k0); if (kk >= 784) kk = 0; \
                    av = *(const float4*)(Ap + kk); }
#define BLOADALL(k0) \
    bv0 = *(const uint4*)(Bt + bofs0 + (k0)); \
    bv1 = *(const uint4*)(Bt + bofs1 + (k0)); \
    bv2 = *(const uint4*)(Bt + bofs2 + (k0)); \
    bv3 = *(const uint4*)(Bt + bofs3 + (k0)); \
    bv4 = *(const uint4*)(Bt + bofs4 + (k0)); \
    bv5 = *(const uint4*)(Bt + bofs5 + (k0));
#define ASPLIT() { u16 h, m, l; \
    split3(av.x, h, m, l); a3h.x = h; a3m.x = m; a3l.x = l; \
    split3(av.y, h, m, l); a3h.y = h; a3m.y = m; a3l.y = l; \
    split3(av.z, h, m, l); a3h.z = h; a3m.z = m; a3l.z = l; \
    split3(av.w, h, m, l); a3h.w = h; a3m.w = m; a3l.w = l; }

    f32x4 acc00 = {0.f, 0.f, 0.f, 0.f};
    f32x4 acc01 = acc00, acc10 = acc00, acc11 = acc00;

    ALOAD(0) BLOADALL(0) ASPLIT()

    // fragment read bases (u16 units)
    const u16* aFr = &As[0][0][lane][0];     // +512/rf, +1024/plane
    const u16* bFr = &Bs[0][w * 2][lane][0]; // +512/cf, +4096/plane

    for (int t = 0; t < 25; ++t) {
        __syncthreads();
        *(ushort4*)(aDst)        = a3h;
        *(ushort4*)(aDst + 1024) = a3m;
        *(ushort4*)(aDst + 2048) = a3l;
        *(uint4*)(bBase + bd0) = bv0;
        *(uint4*)(bBase + bd1) = bv1;
        *(uint4*)(bBase + bd2) = bv2;
        *(uint4*)(bBase + bd3) = bv3;
        *(uint4*)(bBase + bd4) = bv4;
        *(uint4*)(bBase + bd5) = bv5;
        __syncthreads();
        const int kn = (t + 1) << 5;
        if (t < 24) { ALOAD(kn) BLOADALL(kn) }

        bf16x8 a0h = *(const bf16x8*)(aFr);
        bf16x8 a1h = *(const bf16x8*)(aFr + 512);
        bf16x8 a0m = *(const bf16x8*)(aFr + 1024);
        bf16x8 a1m = *(const bf16x8*)(aFr + 1536);
        bf16x8 a0l = *(const bf16x8*)(aFr + 2048);
        bf16x8 a1l = *(const bf16x8*)(aFr + 2560);

        // q=0 (B hi): p = 0,1,2
        bf16x8 bb0 = *(const bf16x8*)(bFr);
        bf16x8 bb1 = *(const bf16x8*)(bFr + 512);
        acc00 = MF(a0h, bb0, acc00); acc01 = MF(a0h, bb1, acc01);
        acc10 = MF(a1h, bb0, acc10); acc11 = MF(a1h, bb1, acc11);
        acc00 = MF(a0m, bb0, acc00); acc01 = MF(a0m, bb1, acc01);
        acc10 = MF(a1m, bb0, acc10); acc11 = MF(a1m, bb1, acc11);
        acc00 = MF(a0l, bb0, acc00); acc01 = MF(a0l, bb1, acc01);
        acc10 = MF(a1l, bb0, acc10); acc11 = MF(a1l, bb1, acc11);
        // q=1 (B mid): p = 0,1
        bf16x8 bc0 = *(const bf16x8*)(bFr + 4096);
        bf16x8 bc1 = *(const bf16x8*)(bFr + 4608);
        acc00 = MF(a0h, bc0, acc00); acc01 = MF(a0h, bc1, acc01);
        acc10 = MF(a1h, bc0, acc10); acc11 = MF(a1h, bc1, acc11);
        acc00 = MF(a0m, bc0, acc00); acc01 = MF(a0m, bc1, acc01);
        acc10 = MF(a1m, bc0, acc10); acc11 = MF(a1m, bc1, acc11);
        // q=2 (B lo): p = 0
        bf16x8 bdq0 = *(const bf16x8*)(bFr + 8192);
        bf16x8 bdq1 = *(const bf16x8*)(bFr + 8704);
        acc00 = MF(a0h, bdq0, acc00); acc01 = MF(a0h, bdq1, acc01);
        acc10 = MF(a1h, bdq0, acc10); acc11 = MF(a1h, bdq1, acc11);

        if (t < 24) ASPLIT()
    }
#undef ALOAD
#undef BLOADALL
#undef ASPLIT

    // epilogue: C row = (lane>>4)*4+r, col = lane&15 within each 16x16 frag
    const float* bias = cb ? biasHi : biasLo;
#define EPI(rf, cf, ACC) { \
        const int col = colBase + w * 32 + (cf) * 16 + (lane & 15); \
        const int cj  = col & 127; \
        const float bb = bias[cj]; \
        const float vh = cb ? vhi[cj] : 0.f; \
        const int rbase = rowBase + (rf) * 16 + ((lane >> 4) << 2); \
        _Pragma("unroll") \
        for (int r = 0; r < 4; ++r) { \
            int row = rbase + r; \
            if (row < N_NODES) { \
                float v = ACC[r] + bb; \
                if (cb) v = fmaf(rowmask[row], vh, v); \
                C[(size_t)row * 256 + col] = v; \
            } } }
    EPI(0, 0, acc00) EPI(0, 1, acc01) EPI(1, 0, acc10) EPI(1, 1, acc11)
#undef EPI
}

// ---------------------------------------------------------------------------
// fillgemm: blocks [0,GEMMB) = MFMA GEMM (long blocks first, LPT);
//           blocks [GEMMB, GEMMB+EBLOCKS) = CSR fill.
// ---------------------------------------------------------------------------
__global__ __launch_bounds__(256)
void fillgemm_kernel(const int* __restrict__ idxs, const float* __restrict__ ea,
                     const int* __restrict__ eoff, int* __restrict__ fillc,
                     float* __restrict__ eas,
                     const float* __restrict__ A, const u16* __restrict__ Bt,
                     const float* __restrict__ biasLo, const float* __restrict__ biasHi,
                     const float* __restrict__ vhi, const float* __restrict__ rowmask,
                     float* __restrict__ C) {
    int gb = blockIdx.x;
    if (gb < GEMMB) {
        gemm_mfma(A, Bt, biasLo, biasHi, vhi, rowmask, C, gb);
        return;
    }
    int i = (gb - GEMMB) * 256 + threadIdx.x;
    if (i < E_EDGES) {
        int s = idxs[i];
        int p = atomicAdd(&fillc[s], 1);
        eas[eoff[s] + p] = ea[i];
    }
}

// ---------------------------------------------------------------------------
// tail16 @ 512 threads (R2 lesson: tail is per-block-latency-bound — all 625
// blocks co-resident, so duration == one block's serial chain. 512 thr halves
// every per-thread chain: 1 GEMM row/thread, 4 msg rows/thread).
// Phase2 reads remapped to contiguous float4 (4tn / 4tn+128): kills the 3.28M
// bank-conflict cycles of the old 8-float-stride mapping. All GEMM phases
// register-double-buffer the B tile (load next during compute).
// ---------------------------------------------------------------------------
__global__ __launch_bounds__(512, 4)
void tail16_kernel(const float* __restrict__ UX1, const float* __restrict__ w1last,
                   const float* __restrict__ eas, const int* __restrict__ eoff,
                   const int* __restrict__ cnt, const float* __restrict__ maskv,
                   const float* __restrict__ M1, const float* __restrict__ WH,
                   const float* __restrict__ bu2, const float* __restrict__ bx2,
                   const float* __restrict__ v2,
                   const float* __restrict__ w2last, const float* __restrict__ M2,
                   const float* __restrict__ pw, const float* __restrict__ pb,
                   float* __restrict__ UX2, float* __restrict__ proj) {
    __shared__ float Bs[16][264];    // B staging (all GEMM phases)
    __shared__ float mhT[128][18];   // msg means [k][m]
    __shared__ float ts[16][132];    // z1 rows
    __shared__ float ebuf[1024];     // CSR edge window
    int rowBase = blockIdx.x * 16;   // 625*16 = 10000 exact
    int tid = threadIdx.x;
    int tr  = tid >> 5;              // 0..15 — this thread's GEMM row
    int tn  = tid & 31;
    int c4  = tn << 2;

    auto msg_phase = [&](const float* __restrict__ U, const float* __restrict__ wl) {
        int d = tid & 127, grp = tid >> 7;   // grp 0..3, wave-uniform
        float w = wl[d];
        float uu[4], sum[4];
        int es[4], ec[4];
#pragma unroll
        for (int it = 0; it < 4; ++it) {
            int n  = rowBase + it * 4 + grp;
            ec[it] = cnt[n];
            es[it] = eoff[n];
            uu[it] = U[(size_t)n * 256 + d];
            sum[it] = 0.f;
        }
        int ebase = eoff[rowBase];
        int eend  = (rowBase + 16 < N_NODES) ? eoff[rowBase + 16] : E_EDGES;
        for (int w0 = ebase; w0 < eend; w0 += 1024) {
            int wlen = min(1024, eend - w0);
            __syncthreads();
            for (int q = tid; q < wlen; q += 512) ebuf[q] = eas[w0 + q];
            __syncthreads();
#pragma unroll
            for (int it = 0; it < 4; ++it) {
                int lo = max(es[it], w0), hiE = min(es[it] + ec[it], w0 + wlen);
                for (int e = lo; e < hiE; ++e)
                    sum[it] += fmaxf(fmaf(ebuf[e - w0], w, uu[it]), 0.f);
            }
        }
#pragma unroll
        for (int it = 0; it < 4; ++it)
            mhT[d][it * 4 + grp] = (ec[it] > 0) ? sum[it] / (float)ec[it] : 0.f;
    };

    // ===== msg1 =====
    msg_phase(UX1, w1last);

    // ===== phase1: ts = relu(xn1 + mhT @ M1), 16x128, 1 row/thread =====
    {
        float a0 = 0.f, a1 = 0.f, a2 = 0.f, a3 = 0.f;
        float4 bv = *(const float4*)(M1 + (size_t)tr * 128 + c4);
        for (int k0 = 0; k0 < 128; k0 += 16) {
            __syncthreads();                 // Bs free + (k0=0) mhT ready
            *(float4*)&Bs[tr][c4] = bv;
            __syncthreads();
            if (k0 + 16 < 128)
                bv = *(const float4*)(M1 + (size_t)(k0 + 16 + tr) * 128 + c4);
#pragma unroll
            for (int k = 0; k < 16; ++k) {
                float a = mhT[k0 + k][tr];
                float4 b = *(const float4*)&Bs[k][c4];
                a0 = fmaf(a, b.x, a0); a1 = fmaf(a, b.y, a1);
                a2 = fmaf(a, b.z, a2); a3 = fmaf(a, b.w, a3);
            }
        }
        int row = rowBase + tr;
        float4 xn = *(const float4*)(UX1 + (size_t)row * 256 + 128 + c4);
        float4 o;
        o.x = fmaxf(a0 + xn.x, 0.f);
        o.y = fmaxf(a1 + xn.y, 0.f);
        o.z = fmaxf(a2 + xn.z, 0.f);
        o.w = fmaxf(a3 + xn.w, 0.f);
        *(float4*)&ts[tr][c4] = o;
    }

    // ===== phase2: UX2 = ts @ WH + bias (+maskv*v2 on hi), 16x256 =====
    {
        float u0 = 0.f, u1 = 0.f, u2 = 0.f, u3 = 0.f;
        float x0 = 0.f, x1 = 0.f, x2 = 0.f, x3 = 0.f;
        int c8 = tn << 3;
        float4 bva = *(const float4*)(WH + (size_t)tr * 256 + c8);
        float4 bvb = *(const float4*)(WH + (size_t)tr * 256 + c8 + 4);
        for (int k0 = 0; k0 < 128; k0 += 16) {
            __syncthreads();                 // orders ts writes / Bs reuse
            *(float4*)&Bs[tr][c8]     = bva;
            *(float4*)&Bs[tr][c8 + 4] = bvb;
            __syncthreads();
            if (k0 + 16 < 128) {
                bva = *(const float4*)(WH + (size_t)(k0 + 16 + tr) * 256 + c8);
                bvb = *(const float4*)(WH + (size_t)(k0 + 16 + tr) * 256 + c8 + 4);
            }
#pragma unroll
            for (int k = 0; k < 16; ++k) {
                float a = ts[tr][k0 + k];
                float4 b0 = *(const float4*)&Bs[k][c4];          // cols 4tn..   (u half)
                float4 b1 = *(const float4*)&Bs[k][c4 + 128];    // cols 128+4tn (x half)
                u0 = fmaf(a, b0.x, u0); u1 = fmaf(a, b0.y, u1);
                u2 = fmaf(a, b0.z, u2); u3 = fmaf(a, b0.w, u3);
                x0 = fmaf(a, b1.x, x0); x1 = fmaf(a, b1.y, x1);
                x2 = fmaf(a, b1.z, x2); x3 = fmaf(a, b1.w, x3);
            }
        }
        int row = rowBase + tr;
        float rm = maskv[row];
        float4 o0, o1;
        o0.x = u0 + bu2[c4 + 0]; o0.y = u1 + bu2[c4 + 1];
        o0.z = u2 + bu2[c4 + 2]; o0.w = u3 + bu2[c4 + 3];
        o1.x = fmaf(rm, v2[c4 + 0], x0 + bx2[c4 + 0]);
        o1.y = fmaf(rm, v2[c4 + 1], x1 + bx2[c4 + 1]);
        o1.z = fmaf(rm, v2[c4 + 2], x2 + bx2[c4 + 2]);
        o1.w = fmaf(rm, v2[c4 + 3], x3 + bx2[c4 + 3]);
        float* orow = UX2 + (size_t)row * 256;
        *(float4*)(orow + c4)       = o0;
        *(float4*)(orow + 128 + c4) = o1;
    }
    __syncthreads();   // UX2 block-visible (own rows only are read below)

    // ===== msg2 =====
    msg_phase(UX2, w2last);

    // ===== phase4: z2 = relu(xn2 + mhT@M2); proj = z2@pw + pb =====
    {
        float a0 = 0.f, a1 = 0.f, a2 = 0.f, a3 = 0.f;
        float4 bv = *(const float4*)(M2 + (size_t)tr * 128 + c4);
        for (int k0 = 0; k0 < 128; k0 += 16) {
            __syncthreads();                 // orders msg2's mhT writes
            *(float4*)&Bs[tr][c4] = bv;
            __syncthreads();
            if (k0 + 16 < 128)
                bv = *(const float4*)(M2 + (size_t)(k0 + 16 + tr) * 128 + c4);
#pragma unroll
            for (int k = 0; k < 16; ++k) {
                float a = mhT[k0 + k][tr];
                float4 b = *(const float4*)&Bs[k][c4];
                a0 = fmaf(a, b.x, a0); a1 = fmaf(a, b.y, a1);
                a2 = fmaf(a, b.z, a2); a3 = fmaf(a, b.w, a3);
            }
        }
        int row = rowBase + tr;
        float4 xn = *(const float4*)(UX2 + (size_t)row * 256 + 128 + c4);
        float t0 = fmaxf(a0 + xn.x, 0.f);
        float t1 = fmaxf(a1 + xn.y, 0.f);
        float t2 = fmaxf(a2 + xn.z, 0.f);
        float t3 = fmaxf(a3 + xn.w, 0.f);
        float pp0 = fmaf(t3, pw[2*(c4+3)],   fmaf(t2, pw[2*(c4+2)],   fmaf(t1, pw[2*(c4+1)],   t0 * pw[2*c4])));
        float pp1 = fmaf(t3, pw[2*(c4+3)+1], fmaf(t2, pw[2*(c4+2)+1], fmaf(t1, pw[2*(c4+1)+1], t0 * pw[2*c4+1])));
        // reduce across the 32-lane half-wave owning this row (off<32 stays in half)
        for (int off = 16; off > 0; off >>= 1) {
            pp0 += __shfl_xor(pp0, off, 64);
            pp1 += __shfl_xor(pp1, off, 64);
        }
        if (tn == 0) {
            proj[2 * row]     = pp0 + pb[0];
            proj[2 * row + 1] = pp1 + pb[1];
        }
    }
}

__global__ void dist_kernel(const float* __restrict__ proj, const int* __restrict__ idxs,
                            float* __restrict__ out, int e) {
    int i = blockIdx.x * blockDim.x + threadIdx.x;
    if (i >= e) return;
    int n = i / KNB;
    int m = idxs[i];
    float2 pn = *(const float2*)(proj + 2 * n);
    float2 pm = *(const float2*)(proj + 2 * m);
    float dx = pn.x - pm.x;
    float dy = pn.y - pm.y;
    out[i] = dx * dx + dy * dy;
}

// ---------------------------------------------------------------------------
extern "C" void kernel_launch(void* const* d_in, const int* in_sizes, int n_in,
                              void* d_out, int out_size, void* d_ws, size_t ws_size,
                              hipStream_t stream) {
    (void)in_sizes; (void)n_in; (void)out_size; (void)ws_size;
    const float* x    = (const float*)d_in[0];
    const float* eatt = (const float*)d_in[1];
    const int*   idxs = (const int*)d_in[2];
    const float* mw1  = (const float*)d_in[3];
    const float* mb1  = (const float*)d_in[4];
    const float* mw2  = (const float*)d_in[5];
    const float* mb2  = (const float*)d_in[6];
    const float* nw1  = (const float*)d_in[7];
    const float* nb1  = (const float*)d_in[8];
    const float* nw2  = (const float*)d_in[9];
    const float* nb2  = (const float*)d_in[10];
    const float* m2w1 = (const float*)d_in[11];
    const float* m2b1 = (const float*)d_in[12];
    const float* m2w2 = (const float*)d_in[13];
    const float* m2b2 = (const float*)d_in[14];
    const float* n2w1 = (const float*)d_in[15];
    const float* n2b1 = (const float*)d_in[16];
    const float* n2w2 = (const float*)d_in[17];
    const float* n2b2 = (const float*)d_in[18];
    float* out = (float*)d_out;

    float* fws   = (float*)d_ws;
    float* UX1   = fws;                   // 10000*256
    float* UX2   = fws + 2560000;         // 10000*256
    float* proj  = fws + 5120000;         // 10000*2
    float* maskv = fws + 5140000;         // 10000
    float* eas   = fws + 5150016;         // 150000
    float* M1    = fws + 5300016;         // 128*128
    float* M2    = fws + 5316400;         // 128*128
    float* WH    = fws + 5332784;         // 128*256
    float* v1    = fws + 5365552;         // 128
    float* v2    = fws + 5365680;         // 128
    float* bu2   = fws + 5365808;         // 128
    float* bx2   = fws + 5365936;         // 128
    int*   cnt   = (int*)(fws + 5366064);
    int*   fillc = cnt + N_NODES;
    int*   eoff  = fillc + N_NODES;
    // Bt aliases UX2: Bt (1.23 MB) is only live scanfold->fillgemm; UX2 is
    // written (fully) and read only inside tail16, after Bt is dead.
    u16*   Bt    = (u16*)(fws + 2560000); // 3*256*800 bf16 bits

    // L1-2: zero cnt, parallel histogram
    hipMemsetAsync(cnt, 0, N_NODES * sizeof(int), stream);
    count_kernel<<<EBLOCKS, 256, 0, stream>>>(idxs, cnt, E_EDGES);

    // L3: prefix-scan (block 0) + weight folds (1..40) + B bf16x3 split (41..56)
    scanfold_kernel<<<57, 256, 0, stream>>>(mw2, mb2, nw1, nb2, nw2,
                                            m2w1, m2b1, m2w2, m2b2, n2w1, n2b1,
                                            M1, M2, WH, v1, v2, bu2, bx2,
                                            cnt, eoff, maskv, fillc, mw1, Bt);

    // L4: MFMA GEMM (626 blocks, first = LPT) + CSR fill (587 blocks)
    fillgemm_kernel<<<GEMMB + EBLOCKS, 256, 0, stream>>>(
        idxs, eatt, eoff, fillc, eas,
        x, Bt, mb1, nb1, v1, maskv, UX1);

    // L5: tail at 16 rows/block, 625 blocks, 512 threads
    tail16_kernel<<<625, 512, 0, stream>>>(UX1, mw1 + 784 * 128, eas, eoff, cnt, maskv,
                                           M1, WH, bu2, bx2, v2,
                                           m2w1 + 128 * 128, M2,
                                           n2w2, n2b2,
                                           UX2, proj);

    // L6: per-edge squared distances
    dist_kernel<<<EBLOCKS, 256, 0, stream>>>(proj, idxs, out, E_EDGES);
}